// Round 1
// baseline (664.249 us; speedup 1.0000x reference)
//
#include <hip/hip_runtime.h>

#define NEG_SLOPE 0.2f

// ---------- wave reduction helpers ----------
static __device__ __forceinline__ float wsum64(float v) {
#pragma unroll
    for (int off = 32; off >= 1; off >>= 1) v += __shfl_xor(v, off, 64);
    return v;
}
static __device__ __forceinline__ float wsum32(float v) {
#pragma unroll
    for (int off = 16; off >= 1; off >>= 1) v += __shfl_xor(v, off, 64);
    return v;
}
static __device__ __forceinline__ float wmax64(float v) {
#pragma unroll
    for (int off = 32; off >= 1; off >>= 1) v = fmaxf(v, __shfl_xor(v, off, 64));
    return v;
}

// ---------- tiny utility kernels ----------
__global__ void k_zero(int* __restrict__ p, int n) {
    int i = blockIdx.x * blockDim.x + threadIdx.x;
    if (i < n) p[i] = 0;
}

// count flow values (0..2) over edges
__global__ void k_flowcnt(const int* __restrict__ edge_attr, int* __restrict__ cnt3, int E) {
    __shared__ int sh[3];
    if (threadIdx.x < 3) sh[threadIdx.x] = 0;
    __syncthreads();
    for (int e = blockIdx.x * blockDim.x + threadIdx.x; e < E; e += gridDim.x * blockDim.x) {
        int f = edge_attr[2 * e];
        f = f < 0 ? 0 : (f > 2 ? 2 : f);
        atomicAdd(&sh[f], 1);
    }
    __syncthreads();
    if (threadIdx.x < 3) atomicAdd(&cnt3[threadIdx.x], sh[threadIdx.x]);
}

// Precompute: posc = pos_table[MAX_POS] @ pos_W + pos_b (constant for ALL edges
// since clip(where(pos>MP,pos,MP),0,MP) == MP identically). Then project the 3
// flow edge-attr vectors and the self-loop mean vector through We1 / We2.
__global__ void k_prep(const float* __restrict__ pos_table, const float* __restrict__ pos_W,
                       const float* __restrict__ pos_b, const float* __restrict__ flow_emb,
                       const float* __restrict__ We1, const float* __restrict__ We2,
                       const int* __restrict__ cnt3,
                       float* __restrict__ eaW1, float* __restrict__ loopW1,
                       float* __restrict__ eaW2, float* __restrict__ loopW2, int E) {
    __shared__ float posc[128];
    __shared__ float lv[128];
    int t = threadIdx.x;
    if (t < 128) {
        const float* row = pos_table + 5120 * 128;
        float a = pos_b[t];
        for (int k = 0; k < 128; ++k) a += row[k] * pos_W[k * 128 + t];
        posc[t] = a;
        float invE = 1.0f / (float)E;
        lv[t] = ((float)cnt3[0] * flow_emb[t] + (float)cnt3[1] * flow_emb[128 + t] +
                 (float)cnt3[2] * flow_emb[256 + t]) * invE + a;
    }
    __syncthreads();
    {   // layer 1 projections, j = 0..255
        int j = t;
        float a0 = 0.f, a1 = 0.f, a2 = 0.f, al = 0.f;
        for (int k = 0; k < 128; ++k) {
            float w = We1[k * 256 + j];
            float pc = posc[k];
            a0 += (flow_emb[k] + pc) * w;
            a1 += (flow_emb[128 + k] + pc) * w;
            a2 += (flow_emb[256 + k] + pc) * w;
            al += lv[k] * w;
        }
        eaW1[j] = a0; eaW1[256 + j] = a1; eaW1[512 + j] = a2; loopW1[j] = al;
    }
    if (t < 32) {  // layer 2 projections
        int j = t;
        float a0 = 0.f, a1 = 0.f, a2 = 0.f, al = 0.f;
        for (int k = 0; k < 128; ++k) {
            float w = We2[k * 32 + j];
            float pc = posc[k];
            a0 += (flow_emb[k] + pc) * w;
            a1 += (flow_emb[128 + k] + pc) * w;
            a2 += (flow_emb[256 + k] + pc) * w;
            al += lv[k] * w;
        }
        eaW2[j] = a0; eaW2[32 + j] = a1; eaW2[64 + j] = a2; loopW2[j] = al;
    }
}

// ---------- CSR-by-dst build ----------
__global__ void k_hist(const int* __restrict__ ei, int* __restrict__ cnt, int E) {
    int e = blockIdx.x * blockDim.x + threadIdx.x;
    if (e < E) atomicAdd(&cnt[ei[E + e]], 1);
}

__global__ __launch_bounds__(256) void k_scan_block(const int* __restrict__ cnt,
                                                    int* __restrict__ rowptr,
                                                    int* __restrict__ bsum, int n) {
    __shared__ int sh[256];
    int b = blockIdx.x, t = threadIdx.x;
    int base = b * 1024 + t * 4;
    int v0 = base + 0 < n ? cnt[base + 0] : 0;
    int v1 = base + 1 < n ? cnt[base + 1] : 0;
    int v2 = base + 2 < n ? cnt[base + 2] : 0;
    int v3 = base + 3 < n ? cnt[base + 3] : 0;
    int tot = v0 + v1 + v2 + v3;
    sh[t] = tot;
    __syncthreads();
    for (int off = 1; off < 256; off <<= 1) {
        int x = (t >= off) ? sh[t - off] : 0;
        __syncthreads();
        sh[t] += x;
        __syncthreads();
    }
    int excl = (t > 0) ? sh[t - 1] : 0;
    if (base + 0 < n) rowptr[base + 0] = excl;
    if (base + 1 < n) rowptr[base + 1] = excl + v0;
    if (base + 2 < n) rowptr[base + 2] = excl + v0 + v1;
    if (base + 3 < n) rowptr[base + 3] = excl + v0 + v1 + v2;
    if (t == 255) bsum[b] = sh[255];
}

__global__ void k_scan_top(int* __restrict__ bsum, int* __restrict__ rowptr, int nb, int n) {
    if (threadIdx.x == 0 && blockIdx.x == 0) {
        int run = 0;
        for (int b = 0; b < nb; ++b) { int x = bsum[b]; bsum[b] = run; run += x; }
        rowptr[n] = run;
    }
}

__global__ void k_scan_add(int* __restrict__ rowptr, const int* __restrict__ bsum,
                           int* __restrict__ wptr, int n) {
    int i = blockIdx.x * blockDim.x + threadIdx.x;
    if (i < n) {
        int v = rowptr[i] + bsum[i >> 10];
        rowptr[i] = v;
        wptr[i] = v;
    }
}

// pack src (16 bits, N=50000<65536) | flow<<16 into dst-sorted order
__global__ void k_scatter(const int* __restrict__ ei, const int* __restrict__ ea,
                          int* __restrict__ wptr, int* __restrict__ packed, int E) {
    int e = blockIdx.x * blockDim.x + threadIdx.x;
    if (e >= E) return;
    int s = ei[e], d = ei[E + e];
    int f = ea[2 * e];
    f = f < 0 ? 0 : (f > 2 ? 2 : f);
    int p = atomicAdd(&wptr[d], 1);
    packed[p] = (s & 0xFFFF) | (f << 16);
}

// ---------- node features ----------
__global__ void k_build_h(const int* __restrict__ x, const float* __restrict__ text_emb,
                          const float* __restrict__ type_emb, float* __restrict__ h, int n) {
    int idx = blockIdx.x * blockDim.x + threadIdx.x;
    if (idx >= n * 128) return;
    int nd = idx >> 7, cc = idx & 127;
    float v;
    if (cc < 64) v = text_emb[(size_t)x[nd * 2] * 64 + cc];
    else         v = type_emb[(size_t)x[nd * 2 + 1] * 64 + (cc - 64)];
    h[idx] = v;
}

// ---------- GEMMs (fp32 vector) ----------
// xl = h@Wl + bl ; xr = h@Wr + br     (N x 128) @ (128 x 256)
__global__ __launch_bounds__(256) void k_gemm1(const float* __restrict__ h,
        const float* __restrict__ Wl, const float* __restrict__ bl,
        const float* __restrict__ Wr, const float* __restrict__ br,
        float* __restrict__ xl, float* __restrict__ xr, int n) {
    __shared__ float sh[16][128];
    int t = threadIdx.x;
    int node0 = blockIdx.x * 16;
    for (int i = t; i < 2048; i += 256) {
        int r = i >> 7, cc = i & 127;
        int nd = node0 + r;
        sh[r][cc] = (nd < n) ? h[(size_t)nd * 128 + cc] : 0.f;
    }
    __syncthreads();
    float accL[16], accR[16];
#pragma unroll
    for (int r = 0; r < 16; ++r) { accL[r] = 0.f; accR[r] = 0.f; }
    int col = t;
    for (int k = 0; k < 128; k += 4) {
        float wl0 = Wl[(k + 0) * 256 + col], wl1 = Wl[(k + 1) * 256 + col];
        float wl2 = Wl[(k + 2) * 256 + col], wl3 = Wl[(k + 3) * 256 + col];
        float wr0 = Wr[(k + 0) * 256 + col], wr1 = Wr[(k + 1) * 256 + col];
        float wr2 = Wr[(k + 2) * 256 + col], wr3 = Wr[(k + 3) * 256 + col];
#pragma unroll
        for (int r = 0; r < 16; ++r) {
            float4 hv = *(const float4*)&sh[r][k];
            accL[r] += hv.x * wl0; accL[r] += hv.y * wl1;
            accL[r] += hv.z * wl2; accL[r] += hv.w * wl3;
            accR[r] += hv.x * wr0; accR[r] += hv.y * wr1;
            accR[r] += hv.z * wr2; accR[r] += hv.w * wr3;
        }
    }
    float blv = bl[col], brv = br[col];
    for (int r = 0; r < 16; ++r) {
        int nd = node0 + r;
        if (nd < n) {
            xl[(size_t)nd * 256 + col] = accL[r] + blv;
            xr[(size_t)nd * 256 + col] = accR[r] + brv;
        }
    }
}

// (N x 256) @ (256 x 32) for both Wl and Wr
__global__ __launch_bounds__(256) void k_gemm2(const float* __restrict__ h2,
        const float* __restrict__ Wl, const float* __restrict__ bl,
        const float* __restrict__ Wr, const float* __restrict__ br,
        float* __restrict__ xl2, float* __restrict__ xr2, int n) {
    __shared__ float sh[32][256];
    int t = threadIdx.x;
    int node0 = blockIdx.x * 32;
    for (int i = t; i < 32 * 256; i += 256) {
        int r = i >> 8, cc = i & 255;
        int nd = node0 + r;
        sh[r][cc] = (nd < n) ? h2[(size_t)nd * 256 + cc] : 0.f;
    }
    __syncthreads();
    int col = t & 31;
    int mat = (t >> 5) & 1;
    int rg = t >> 6;  // 0..3, 8 nodes each
    const float* W = mat ? Wr : Wl;
    float acc[8];
#pragma unroll
    for (int r = 0; r < 8; ++r) acc[r] = 0.f;
    for (int k = 0; k < 256; k += 4) {
        float w0 = W[(k + 0) * 32 + col], w1 = W[(k + 1) * 32 + col];
        float w2 = W[(k + 2) * 32 + col], w3 = W[(k + 3) * 32 + col];
#pragma unroll
        for (int r = 0; r < 8; ++r) {
            float4 hv = *(const float4*)&sh[rg * 8 + r][k];
            acc[r] += hv.x * w0; acc[r] += hv.y * w1;
            acc[r] += hv.z * w2; acc[r] += hv.w * w3;
        }
    }
    float bv = mat ? br[col] : bl[col];
    float* dst = mat ? xr2 : xl2;
    for (int r = 0; r < 8; ++r) {
        int nd = node0 + rg * 8 + r;
        if (nd < n) dst[(size_t)nd * 32 + col] = acc[r] + bv;
    }
}

// ---------- GAT edge aggregation, one wave per destination node ----------
static __device__ __forceinline__ float edot4(float mx_, float my, float mz, float mw,
                                              const float4 av) {
    float x0 = mx_ > 0.f ? mx_ : NEG_SLOPE * mx_;
    float x1 = my > 0.f ? my : NEG_SLOPE * my;
    float x2 = mz > 0.f ? mz : NEG_SLOPE * mz;
    float x3 = mw > 0.f ? mw : NEG_SLOPE * mw;
    float p = x0 * av.x + x1 * av.y + x2 * av.z + x3 * av.w;
    return wsum64(p);
}

__global__ __launch_bounds__(256) void k_gat256(const float* __restrict__ xl,
        const float* __restrict__ xr, const int* __restrict__ rowptr,
        const int* __restrict__ packed, const float* __restrict__ eaW,
        const float* __restrict__ loopW, const float* __restrict__ att,
        const float* __restrict__ bias, float* __restrict__ out, int n) {
    int wid = (blockIdx.x * blockDim.x + threadIdx.x) >> 6;
    int lane = threadIdx.x & 63;
    if (wid >= n) return;
    int d = wid;
    int c = lane * 4;
    float4 xrd = *(const float4*)(xr + (size_t)d * 256 + c);
    float4 xld = *(const float4*)(xl + (size_t)d * 256 + c);
    float4 av  = *(const float4*)(att + c);
    float4 ea0 = *(const float4*)(eaW + c);
    float4 ea1 = *(const float4*)(eaW + 256 + c);
    float4 ea2 = *(const float4*)(eaW + 512 + c);
    float4 lw  = *(const float4*)(loopW + c);
    // self loop (src = dst, attr = loop mean)
    float e = edot4(xld.x + xrd.x + lw.x, xld.y + xrd.y + lw.y,
                    xld.z + xrd.z + lw.z, xld.w + xrd.w + lw.w, av);
    float mx = e, den = 1.f;
    float4 acc = xld;
    int p0 = rowptr[d], p1 = rowptr[d + 1];
    for (int p = p0; p < p1; ++p) {
        int pk = packed[p];
        int s = pk & 0xFFFF;
        int f = pk >> 16;
        float4 xs = *(const float4*)(xl + (size_t)s * 256 + c);
        float4 eav = (f == 0) ? ea0 : ((f == 1) ? ea1 : ea2);
        float ce = edot4(xs.x + xrd.x + eav.x, xs.y + xrd.y + eav.y,
                         xs.z + xrd.z + eav.z, xs.w + xrd.w + eav.w, av);
        if (ce > mx) {
            float sc = __expf(mx - ce);
            den *= sc; acc.x *= sc; acc.y *= sc; acc.z *= sc; acc.w *= sc;
            mx = ce;
        }
        float w = __expf(ce - mx);
        den += w;
        acc.x += w * xs.x; acc.y += w * xs.y; acc.z += w * xs.z; acc.w += w * xs.w;
    }
    float inv = 1.f / den;
    float4 bv = *(const float4*)(bias + c);
    float4 o;
    o.x = acc.x * inv + bv.x; o.y = acc.y * inv + bv.y;
    o.z = acc.z * inv + bv.z; o.w = acc.w * inv + bv.w;
    *(float4*)(out + (size_t)d * 256 + c) = o;
}

__global__ __launch_bounds__(256) void k_gat32(const float* __restrict__ xl,
        const float* __restrict__ xr, const int* __restrict__ rowptr,
        const int* __restrict__ packed, const float* __restrict__ eaW,
        const float* __restrict__ loopW, const float* __restrict__ att,
        const float* __restrict__ bias, float* __restrict__ out, int n) {
    int wid = (blockIdx.x * blockDim.x + threadIdx.x) >> 6;
    int lane = threadIdx.x & 63;
    if (wid >= n) return;
    int d = wid;
    int c = lane & 31;  // two redundant halves, each holds all 32 dims
    float xrd = xr[(size_t)d * 32 + c];
    float xld = xl[(size_t)d * 32 + c];
    float av = att[c];
    float ea0 = eaW[c], ea1 = eaW[32 + c], ea2 = eaW[64 + c];
    float lw = loopW[c];
    float m = xld + xrd + lw;
    m = m > 0.f ? m : NEG_SLOPE * m;
    float e = wsum32(m * av);
    float mx = e, den = 1.f, acc = xld;
    int p0 = rowptr[d], p1 = rowptr[d + 1];
    for (int p = p0; p < p1; ++p) {
        int pk = packed[p];
        int s = pk & 0xFFFF;
        int f = pk >> 16;
        float xs = xl[(size_t)s * 32 + c];
        float eav = (f == 0) ? ea0 : ((f == 1) ? ea1 : ea2);
        float mm = xs + xrd + eav;
        mm = mm > 0.f ? mm : NEG_SLOPE * mm;
        float ce = wsum32(mm * av);
        if (ce > mx) {
            float sc = __expf(mx - ce);
            den *= sc; acc *= sc; mx = ce;
        }
        float w = __expf(ce - mx);
        den += w;
        acc += w * xs;
    }
    if (lane < 32) out[(size_t)d * 32 + c] = acc / den + bias[c];
}

// ---------- mean over nodes + policy head ----------
__global__ __launch_bounds__(256) void k_mean(const float* __restrict__ out2,
                                              float* __restrict__ gsum, int n) {
    __shared__ float sh[256];
    int t = threadIdx.x;
    int c = t & 31, g = t >> 5;
    float acc = 0.f;
    for (int nd = blockIdx.x * 8 + g; nd < n; nd += gridDim.x * 8)
        acc += out2[(size_t)nd * 32 + c];
    sh[t] = acc;
    __syncthreads();
    if (t < 32) {
        float s2 = 0.f;
#pragma unroll
        for (int gg = 0; gg < 8; ++gg) s2 += sh[gg * 32 + c];
        atomicAdd(&gsum[c], s2);
    }
}

__global__ void k_final(const float* __restrict__ gsum, const float* __restrict__ policy_W,
                        const float* __restrict__ policy_b, float* __restrict__ out, int n) {
    int t = threadIdx.x;  // 0..63 — one wave
    float invN = 1.0f / (float)n;
    float acc = policy_b[t];
    for (int cc = 0; cc < 32; ++cc) acc += gsum[cc] * invN * policy_W[cc * 64 + t];
    float mx = wmax64(acc);
    float ex = __expf(acc - mx);
    float s = wsum64(ex);
    out[t] = ex / s;
}

extern "C" void kernel_launch(void* const* d_in, const int* in_sizes, int n_in,
                              void* d_out, int out_size, void* d_ws, size_t ws_size,
                              hipStream_t stream) {
    const int* x          = (const int*)d_in[0];
    const int* edge_index = (const int*)d_in[1];
    const int* edge_attr  = (const int*)d_in[2];
    const float* text_emb = (const float*)d_in[3];
    const float* type_emb = (const float*)d_in[4];
    const float* flow_emb = (const float*)d_in[5];
    const float* pos_table= (const float*)d_in[6];
    const float* pos_W    = (const float*)d_in[7];
    const float* pos_b    = (const float*)d_in[8];
    const float* c1_Wl    = (const float*)d_in[9];
    const float* c1_bl    = (const float*)d_in[10];
    const float* c1_Wr    = (const float*)d_in[11];
    const float* c1_br    = (const float*)d_in[12];
    const float* c1_We    = (const float*)d_in[13];
    const float* c1_att   = (const float*)d_in[14];
    const float* c1_bias  = (const float*)d_in[15];
    const float* c2_Wl    = (const float*)d_in[16];
    const float* c2_bl    = (const float*)d_in[17];
    const float* c2_Wr    = (const float*)d_in[18];
    const float* c2_br    = (const float*)d_in[19];
    const float* c2_We    = (const float*)d_in[20];
    const float* c2_att   = (const float*)d_in[21];
    const float* c2_bias  = (const float*)d_in[22];
    const float* policy_W = (const float*)d_in[23];
    const float* policy_b = (const float*)d_in[24];
    float* out = (float*)d_out;

    const int N = in_sizes[0] / 2;   // 50000
    const int E = in_sizes[1] / 2;   // 800000

    // ---- workspace layout (fp32 elements) ----
    float* fws = (float*)d_ws;
    float* h   = fws;                 // N*128 = 6,400,000
    float* xl1 = fws + 6400000;       // N*256
    float* xr1 = fws + 19200000;      // N*256
    float* h2  = fws + 32000000;      // N*256
    // region A (h) is dead after gemm1 → reuse for layer-2 buffers
    float* xl2  = h;                  // N*32
    float* xr2  = h + 1600000;        // N*32
    float* out2 = h + 3200000;        // N*32
    int* iws    = (int*)(fws + 44800000);
    int* cntw   = iws;                // N (histogram, then write-cursor)
    int* rowptr = iws + N;            // N+1
    int* packed = iws + 2 * N + 1;    // E
    int* bsum   = packed + E;         // 64
    int* cnt3   = bsum + 64;          // 4
    size_t tofs = (size_t)(2 * N + 1 + E + 64 + 4);
    tofs = (tofs + 3) & ~(size_t)3;   // keep 16B alignment for float4 table loads
    float* tabs  = (float*)(iws + tofs);
    float* eaW1   = tabs;             // 3*256
    float* loopW1 = tabs + 768;       // 256
    float* eaW2   = tabs + 1024;      // 3*32
    float* loopW2 = tabs + 1120;      // 32
    float* gsum   = tabs + 1152;      // 32

    // ---- init (ws is poisoned 0xAA every call) ----
    k_zero<<<(N + 255) / 256, 256, 0, stream>>>(cntw, N);
    k_zero<<<1, 256, 0, stream>>>(cnt3, 4);
    k_zero<<<1, 256, 0, stream>>>((int*)gsum, 32);

    // ---- constant edge-attr projections ----
    k_flowcnt<<<512, 256, 0, stream>>>(edge_attr, cnt3, E);
    k_prep<<<1, 256, 0, stream>>>(pos_table, pos_W, pos_b, flow_emb, c1_We, c2_We,
                                  cnt3, eaW1, loopW1, eaW2, loopW2, E);

    // ---- CSR build (dst-sorted edge list) ----
    k_hist<<<(E + 255) / 256, 256, 0, stream>>>(edge_index, cntw, E);
    int nb = (N + 1023) / 1024;
    k_scan_block<<<nb, 256, 0, stream>>>(cntw, rowptr, bsum, N);
    k_scan_top<<<1, 64, 0, stream>>>(bsum, rowptr, nb, N);
    k_scan_add<<<(N + 255) / 256, 256, 0, stream>>>(rowptr, bsum, cntw, N);
    k_scatter<<<(E + 255) / 256, 256, 0, stream>>>(edge_index, edge_attr, cntw, packed, E);

    // ---- node features + layer 1 ----
    k_build_h<<<(N * 128 + 255) / 256, 256, 0, stream>>>(x, text_emb, type_emb, h, N);
    k_gemm1<<<(N + 15) / 16, 256, 0, stream>>>(h, c1_Wl, c1_bl, c1_Wr, c1_br, xl1, xr1, N);
    k_gat256<<<(N + 3) / 4, 256, 0, stream>>>(xl1, xr1, rowptr, packed, eaW1, loopW1,
                                              c1_att, c1_bias, h2, N);

    // ---- layer 2 ----
    k_gemm2<<<(N + 31) / 32, 256, 0, stream>>>(h2, c2_Wl, c2_bl, c2_Wr, c2_br, xl2, xr2, N);
    k_gat32<<<(N + 3) / 4, 256, 0, stream>>>(xl2, xr2, rowptr, packed, eaW2, loopW2,
                                             c2_att, c2_bias, out2, N);

    // ---- readout ----
    k_mean<<<256, 256, 0, stream>>>(out2, gsum, N);
    k_final<<<1, 64, 0, stream>>>(gsum, policy_W, policy_b, out, N);
}

// Round 2
// 581.955 us; speedup vs baseline: 1.1414x; 1.1414x over previous
//
#include <hip/hip_runtime.h>

#define NEG_SLOPE 0.2f

// leaky_relu(m) = 0.6*m + 0.4*|m|  (exact for slope 0.2)
static __device__ __forceinline__ float lrelu(float m) {
    return fmaf(0.4f, fabsf(m), 0.6f * m);
}

static __device__ __forceinline__ float wsum64(float v) {
#pragma unroll
    for (int off = 32; off >= 1; off >>= 1) v += __shfl_xor(v, off, 64);
    return v;
}
static __device__ __forceinline__ float wsum32(float v) {
#pragma unroll
    for (int off = 16; off >= 1; off >>= 1) v += __shfl_xor(v, off, 64);
    return v;
}
static __device__ __forceinline__ float wmax64(float v) {
#pragma unroll
    for (int off = 32; off >= 1; off >>= 1) v = fmaxf(v, __shfl_xor(v, off, 64));
    return v;
}

// per-lane partial of leakyrelu(xs + pre) . av  over this lane's 4 dims
static __device__ __forceinline__ float ldot4(const float4 xs, const float4 pre,
                                              const float4 av) {
    float q;
    q  = lrelu(xs.x + pre.x) * av.x;
    q += lrelu(xs.y + pre.y) * av.y;
    q += lrelu(xs.z + pre.z) * av.z;
    q += lrelu(xs.w + pre.w) * av.w;
    return q;
}

// ---------- init ----------
__global__ void k_zero_all(int* __restrict__ cntw, int n, int* __restrict__ cnt3,
                           int* __restrict__ gsum) {
    int i = blockIdx.x * blockDim.x + threadIdx.x;
    if (i < n) cntw[i] = 0;
    if (i < 4) cnt3[i] = 0;
    if (i < 32) gsum[i] = 0;
}

// count flow values (0..2) over edges
__global__ void k_flowcnt(const int* __restrict__ edge_attr, int* __restrict__ cnt3, int E) {
    __shared__ int sh[3];
    if (threadIdx.x < 3) sh[threadIdx.x] = 0;
    __syncthreads();
    for (int e = blockIdx.x * blockDim.x + threadIdx.x; e < E; e += gridDim.x * blockDim.x) {
        int f = edge_attr[2 * e];
        f = f < 0 ? 0 : (f > 2 ? 2 : f);
        atomicAdd(&sh[f], 1);
    }
    __syncthreads();
    if (threadIdx.x < 3) atomicAdd(&cnt3[threadIdx.x], sh[threadIdx.x]);
}

// posc = pos_table[MAX_POS] @ pos_W + pos_b is constant for ALL edges
// (clip(where(pos>MP,pos,MP),0,MP) == MP identically). Project 3 flow vectors
// + self-loop mean vector through We1 / We2.
__global__ void k_prep(const float* __restrict__ pos_table, const float* __restrict__ pos_W,
                       const float* __restrict__ pos_b, const float* __restrict__ flow_emb,
                       const float* __restrict__ We1, const float* __restrict__ We2,
                       const int* __restrict__ cnt3,
                       float* __restrict__ eaW1, float* __restrict__ loopW1,
                       float* __restrict__ eaW2, float* __restrict__ loopW2, int E) {
    __shared__ float posc[128];
    __shared__ float lv[128];
    int t = threadIdx.x;
    if (t < 128) {
        const float* row = pos_table + 5120 * 128;
        float a = pos_b[t];
        for (int k = 0; k < 128; ++k) a += row[k] * pos_W[k * 128 + t];
        posc[t] = a;
        float invE = 1.0f / (float)E;
        lv[t] = ((float)cnt3[0] * flow_emb[t] + (float)cnt3[1] * flow_emb[128 + t] +
                 (float)cnt3[2] * flow_emb[256 + t]) * invE + a;
    }
    __syncthreads();
    {   // layer 1 projections, j = 0..255
        int j = t;
        float a0 = 0.f, a1 = 0.f, a2 = 0.f, al = 0.f;
        for (int k = 0; k < 128; ++k) {
            float w = We1[k * 256 + j];
            float pc = posc[k];
            a0 += (flow_emb[k] + pc) * w;
            a1 += (flow_emb[128 + k] + pc) * w;
            a2 += (flow_emb[256 + k] + pc) * w;
            al += lv[k] * w;
        }
        eaW1[j] = a0; eaW1[256 + j] = a1; eaW1[512 + j] = a2; loopW1[j] = al;
    }
    if (t < 32) {  // layer 2 projections
        int j = t;
        float a0 = 0.f, a1 = 0.f, a2 = 0.f, al = 0.f;
        for (int k = 0; k < 128; ++k) {
            float w = We2[k * 32 + j];
            float pc = posc[k];
            a0 += (flow_emb[k] + pc) * w;
            a1 += (flow_emb[128 + k] + pc) * w;
            a2 += (flow_emb[256 + k] + pc) * w;
            al += lv[k] * w;
        }
        eaW2[j] = a0; eaW2[32 + j] = a1; eaW2[64 + j] = a2; loopW2[j] = al;
    }
}

// ---------- CSR-by-dst build ----------
__global__ void k_hist(const int* __restrict__ ei, int* __restrict__ cnt, int E) {
    int e = blockIdx.x * blockDim.x + threadIdx.x;
    if (e < E) atomicAdd(&cnt[ei[E + e]], 1);
}

__global__ __launch_bounds__(256) void k_scan_block(const int* __restrict__ cnt,
                                                    int* __restrict__ rowptr,
                                                    int* __restrict__ bsum, int n) {
    __shared__ int sh[256];
    int b = blockIdx.x, t = threadIdx.x;
    int base = b * 1024 + t * 4;
    int v0 = base + 0 < n ? cnt[base + 0] : 0;
    int v1 = base + 1 < n ? cnt[base + 1] : 0;
    int v2 = base + 2 < n ? cnt[base + 2] : 0;
    int v3 = base + 3 < n ? cnt[base + 3] : 0;
    int tot = v0 + v1 + v2 + v3;
    sh[t] = tot;
    __syncthreads();
    for (int off = 1; off < 256; off <<= 1) {
        int x = (t >= off) ? sh[t - off] : 0;
        __syncthreads();
        sh[t] += x;
        __syncthreads();
    }
    int excl = (t > 0) ? sh[t - 1] : 0;
    if (base + 0 < n) rowptr[base + 0] = excl;
    if (base + 1 < n) rowptr[base + 1] = excl + v0;
    if (base + 2 < n) rowptr[base + 2] = excl + v0 + v1;
    if (base + 3 < n) rowptr[base + 3] = excl + v0 + v1 + v2;
    if (t == 255) bsum[b] = sh[255];
}

__global__ void k_scan_top(int* __restrict__ bsum, int* __restrict__ rowptr, int nb, int n) {
    if (threadIdx.x == 0 && blockIdx.x == 0) {
        int run = 0;
        for (int b = 0; b < nb; ++b) { int x = bsum[b]; bsum[b] = run; run += x; }
        rowptr[n] = run;
    }
}

__global__ void k_scan_add(int* __restrict__ rowptr, const int* __restrict__ bsum,
                           int* __restrict__ wptr, int n) {
    int i = blockIdx.x * blockDim.x + threadIdx.x;
    if (i < n) {
        int v = rowptr[i] + bsum[i >> 10];
        rowptr[i] = v;
        wptr[i] = v;
    }
}

// pack src (16 bits, N<65536) | flow<<16 into dst-sorted order
__global__ void k_scatter(const int* __restrict__ ei, const int* __restrict__ ea,
                          int* __restrict__ wptr, int* __restrict__ packed, int E) {
    int e = blockIdx.x * blockDim.x + threadIdx.x;
    if (e >= E) return;
    int s = ei[e], d = ei[E + e];
    int f = ea[2 * e];
    f = f < 0 ? 0 : (f > 2 ? 2 : f);
    int p = atomicAdd(&wptr[d], 1);
    packed[p] = (s & 0xFFFF) | (f << 16);
}

// ---------- GEMM 1 with fused embedding gather ----------
// xl = h@Wl + bl ; xr = h@Wr + br  where h = [text_emb[x0] | type_emb[x1]]
__global__ __launch_bounds__(256) void k_gemm1(const int* __restrict__ x,
        const float* __restrict__ text_emb, const float* __restrict__ type_emb,
        const float* __restrict__ Wl, const float* __restrict__ bl,
        const float* __restrict__ Wr, const float* __restrict__ br,
        float* __restrict__ xl, float* __restrict__ xr, int n) {
    __shared__ float sh[16][128];
    int t = threadIdx.x;
    int node0 = blockIdx.x * 16;
    for (int i = t; i < 2048; i += 256) {
        int r = i >> 7, cc = i & 127;
        int nd = node0 + r;
        float v = 0.f;
        if (nd < n) {
            v = (cc < 64) ? text_emb[(size_t)x[nd * 2] * 64 + cc]
                          : type_emb[(size_t)x[nd * 2 + 1] * 64 + (cc - 64)];
        }
        sh[r][cc] = v;
    }
    __syncthreads();
    float accL[16], accR[16];
#pragma unroll
    for (int r = 0; r < 16; ++r) { accL[r] = 0.f; accR[r] = 0.f; }
    int col = t;
    for (int k = 0; k < 128; k += 4) {
        float wl0 = Wl[(k + 0) * 256 + col], wl1 = Wl[(k + 1) * 256 + col];
        float wl2 = Wl[(k + 2) * 256 + col], wl3 = Wl[(k + 3) * 256 + col];
        float wr0 = Wr[(k + 0) * 256 + col], wr1 = Wr[(k + 1) * 256 + col];
        float wr2 = Wr[(k + 2) * 256 + col], wr3 = Wr[(k + 3) * 256 + col];
#pragma unroll
        for (int r = 0; r < 16; ++r) {
            float4 hv = *(const float4*)&sh[r][k];
            accL[r] += hv.x * wl0; accL[r] += hv.y * wl1;
            accL[r] += hv.z * wl2; accL[r] += hv.w * wl3;
            accR[r] += hv.x * wr0; accR[r] += hv.y * wr1;
            accR[r] += hv.z * wr2; accR[r] += hv.w * wr3;
        }
    }
    float blv = bl[col], brv = br[col];
    for (int r = 0; r < 16; ++r) {
        int nd = node0 + r;
        if (nd < n) {
            xl[(size_t)nd * 256 + col] = accL[r] + blv;
            xr[(size_t)nd * 256 + col] = accR[r] + brv;
        }
    }
}

// (N x 256) @ (256 x 32) for both Wl and Wr
__global__ __launch_bounds__(256) void k_gemm2(const float* __restrict__ h2,
        const float* __restrict__ Wl, const float* __restrict__ bl,
        const float* __restrict__ Wr, const float* __restrict__ br,
        float* __restrict__ xl2, float* __restrict__ xr2, int n) {
    __shared__ float sh[32][256];
    int t = threadIdx.x;
    int node0 = blockIdx.x * 32;
    for (int i = t; i < 32 * 256; i += 256) {
        int r = i >> 8, cc = i & 255;
        int nd = node0 + r;
        sh[r][cc] = (nd < n) ? h2[(size_t)nd * 256 + cc] : 0.f;
    }
    __syncthreads();
    int col = t & 31;
    int mat = (t >> 5) & 1;
    int rg = t >> 6;  // 0..3, 8 nodes each
    const float* W = mat ? Wr : Wl;
    float acc[8];
#pragma unroll
    for (int r = 0; r < 8; ++r) acc[r] = 0.f;
    for (int k = 0; k < 256; k += 4) {
        float w0 = W[(k + 0) * 32 + col], w1 = W[(k + 1) * 32 + col];
        float w2 = W[(k + 2) * 32 + col], w3 = W[(k + 3) * 32 + col];
#pragma unroll
        for (int r = 0; r < 8; ++r) {
            float4 hv = *(const float4*)&sh[rg * 8 + r][k];
            acc[r] += hv.x * w0; acc[r] += hv.y * w1;
            acc[r] += hv.z * w2; acc[r] += hv.w * w3;
        }
    }
    float bv = mat ? br[col] : bl[col];
    float* dst = mat ? xr2 : xl2;
    for (int r = 0; r < 8; ++r) {
        int nd = node0 + rg * 8 + r;
        if (nd < n) dst[(size_t)nd * 32 + col] = acc[r] + bv;
    }
}

// ---------- GAT layer 1: one wave per dst, 4 edges in flight, no online max ----------
__global__ __launch_bounds__(256) void k_gat256(const float* __restrict__ xl,
        const float* __restrict__ xr, const int* __restrict__ rowptr,
        const int* __restrict__ packed, const float* __restrict__ eaW,
        const float* __restrict__ loopW, const float* __restrict__ att,
        const float* __restrict__ bias, float* __restrict__ out, int n) {
    int wid = (blockIdx.x * blockDim.x + threadIdx.x) >> 6;
    int lane = threadIdx.x & 63;
    if (wid >= n) return;
    int d = wid;
    int c = lane * 4;
    float4 xrd = *(const float4*)(xr + (size_t)d * 256 + c);
    float4 xld = *(const float4*)(xl + (size_t)d * 256 + c);
    float4 av  = *(const float4*)(att + c);
    // premixed per-flow vectors: r_f = xr[d] + eaW[f]
    float4 r0 = *(const float4*)(eaW + c);
    float4 r1 = *(const float4*)(eaW + 256 + c);
    float4 r2 = *(const float4*)(eaW + 512 + c);
    r0.x += xrd.x; r0.y += xrd.y; r0.z += xrd.z; r0.w += xrd.w;
    r1.x += xrd.x; r1.y += xrd.y; r1.z += xrd.z; r1.w += xrd.w;
    r2.x += xrd.x; r2.y += xrd.y; r2.z += xrd.z; r2.w += xrd.w;
    // self loop
    float4 lw = *(const float4*)(loopW + c);
    float4 sl; sl.x = xrd.x + lw.x; sl.y = xrd.y + lw.y;
    sl.z = xrd.z + lw.z; sl.w = xrd.w + lw.w;
    float q = wsum64(ldot4(xld, sl, av));
    float wself = __expf(q);
    float den = wself;
    float4 acc;
    acc.x = wself * xld.x; acc.y = wself * xld.y;
    acc.z = wself * xld.z; acc.w = wself * xld.w;

    int p0 = rowptr[d], p1 = rowptr[d + 1];
    int p = p0;
    for (; p + 4 <= p1; p += 4) {
        int pk0 = packed[p], pk1 = packed[p + 1];
        int pk2 = packed[p + 2], pk3 = packed[p + 3];
        const float4 xs0 = *(const float4*)(xl + (size_t)(pk0 & 0xFFFF) * 256 + c);
        const float4 xs1 = *(const float4*)(xl + (size_t)(pk1 & 0xFFFF) * 256 + c);
        const float4 xs2 = *(const float4*)(xl + (size_t)(pk2 & 0xFFFF) * 256 + c);
        const float4 xs3 = *(const float4*)(xl + (size_t)(pk3 & 0xFFFF) * 256 + c);
        int f0 = pk0 >> 16, f1 = pk1 >> 16, f2 = pk2 >> 16, f3 = pk3 >> 16;
        float4 pr0 = (f0 == 0) ? r0 : ((f0 == 1) ? r1 : r2);
        float4 pr1 = (f1 == 0) ? r0 : ((f1 == 1) ? r1 : r2);
        float4 pr2 = (f2 == 0) ? r0 : ((f2 == 1) ? r1 : r2);
        float4 pr3 = (f3 == 0) ? r0 : ((f3 == 1) ? r1 : r2);
        float q0 = ldot4(xs0, pr0, av);
        float q1 = ldot4(xs1, pr1, av);
        float q2 = ldot4(xs2, pr2, av);
        float q3 = ldot4(xs3, pr3, av);
#pragma unroll
        for (int off = 32; off >= 1; off >>= 1) {
            q0 += __shfl_xor(q0, off, 64);
            q1 += __shfl_xor(q1, off, 64);
            q2 += __shfl_xor(q2, off, 64);
            q3 += __shfl_xor(q3, off, 64);
        }
        float w0 = __expf(q0), w1 = __expf(q1);
        float w2 = __expf(q2), w3 = __expf(q3);
        den += (w0 + w1) + (w2 + w3);
        acc.x += w0 * xs0.x + w1 * xs1.x + w2 * xs2.x + w3 * xs3.x;
        acc.y += w0 * xs0.y + w1 * xs1.y + w2 * xs2.y + w3 * xs3.y;
        acc.z += w0 * xs0.z + w1 * xs1.z + w2 * xs2.z + w3 * xs3.z;
        acc.w += w0 * xs0.w + w1 * xs1.w + w2 * xs2.w + w3 * xs3.w;
    }
    for (; p < p1; ++p) {
        int pk = packed[p];
        const float4 xs = *(const float4*)(xl + (size_t)(pk & 0xFFFF) * 256 + c);
        int f = pk >> 16;
        float4 pr = (f == 0) ? r0 : ((f == 1) ? r1 : r2);
        float qq = wsum64(ldot4(xs, pr, av));
        float w = __expf(qq);
        den += w;
        acc.x += w * xs.x; acc.y += w * xs.y; acc.z += w * xs.z; acc.w += w * xs.w;
    }
    float inv = 1.f / den;
    float4 bv = *(const float4*)(bias + c);
    float4 o;
    o.x = acc.x * inv + bv.x; o.y = acc.y * inv + bv.y;
    o.z = acc.z * inv + bv.z; o.w = acc.w * inv + bv.w;
    *(float4*)(out + (size_t)d * 256 + c) = o;
}

// ---------- GAT layer 2: one wave per dst, two half-wave edge streams ----------
__global__ __launch_bounds__(256) void k_gat32(const float* __restrict__ xl,
        const float* __restrict__ xr, const int* __restrict__ rowptr,
        const int* __restrict__ packed, const float* __restrict__ eaW,
        const float* __restrict__ loopW, const float* __restrict__ att,
        const float* __restrict__ bias, float* __restrict__ out, int n) {
    int wid = (blockIdx.x * blockDim.x + threadIdx.x) >> 6;
    int lane = threadIdx.x & 63;
    if (wid >= n) return;
    int d = wid;
    int half = lane >> 5;
    int c = lane & 31;
    float xrd = xr[(size_t)d * 32 + c];
    float xld = xl[(size_t)d * 32 + c];
    float av = att[c];
    float r0 = eaW[c] + xrd, r1 = eaW[32 + c] + xrd, r2 = eaW[64 + c] + xrd;
    float den = 0.f, acc = 0.f;
    if (half == 0) {  // self loop counted once
        float lw = loopW[c];
        float q = wsum32(lrelu(xld + xrd + lw) * av);
        float wself = __expf(q);
        den = wself;
        acc = wself * xld;
    }
    int p0 = rowptr[d], p1 = rowptr[d + 1];
    int p = p0 + half;
    // each half-wave walks its own stride-2 stream; unroll 2 (4 edges in flight)
    for (; p + 2 < p1; p += 4) {
        int pkA = packed[p], pkB = packed[p + 2];
        float xsA = xl[(size_t)(pkA & 0xFFFF) * 32 + c];
        float xsB = xl[(size_t)(pkB & 0xFFFF) * 32 + c];
        int fA = pkA >> 16, fB = pkB >> 16;
        float prA = (fA == 0) ? r0 : ((fA == 1) ? r1 : r2);
        float prB = (fB == 0) ? r0 : ((fB == 1) ? r1 : r2);
        float qA = lrelu(xsA + prA) * av;
        float qB = lrelu(xsB + prB) * av;
#pragma unroll
        for (int off = 16; off >= 1; off >>= 1) {
            qA += __shfl_xor(qA, off, 64);
            qB += __shfl_xor(qB, off, 64);
        }
        float wA = __expf(qA), wB = __expf(qB);
        den += wA + wB;
        acc += wA * xsA + wB * xsB;
    }
    for (; p < p1; p += 2) {
        int pk = packed[p];
        float xs = xl[(size_t)(pk & 0xFFFF) * 32 + c];
        int f = pk >> 16;
        float pr = (f == 0) ? r0 : ((f == 1) ? r1 : r2);
        float q = wsum32(lrelu(xs + pr) * av);
        float w = __expf(q);
        den += w;
        acc += w * xs;
    }
    // combine the two halves
    den += __shfl_xor(den, 32, 64);
    acc += __shfl_xor(acc, 32, 64);
    if (lane < 32) out[(size_t)d * 32 + c] = acc / den + bias[c];
}

// ---------- mean over nodes + policy head ----------
__global__ __launch_bounds__(256) void k_mean(const float* __restrict__ out2,
                                              float* __restrict__ gsum, int n) {
    __shared__ float sh[256];
    int t = threadIdx.x;
    int c = t & 31, g = t >> 5;
    float acc = 0.f;
    for (int nd = blockIdx.x * 8 + g; nd < n; nd += gridDim.x * 8)
        acc += out2[(size_t)nd * 32 + c];
    sh[t] = acc;
    __syncthreads();
    if (t < 32) {
        float s2 = 0.f;
#pragma unroll
        for (int gg = 0; gg < 8; ++gg) s2 += sh[gg * 32 + c];
        atomicAdd(&gsum[c], s2);
    }
}

__global__ void k_final(const float* __restrict__ gsum, const float* __restrict__ policy_W,
                        const float* __restrict__ policy_b, float* __restrict__ out, int n) {
    int t = threadIdx.x;  // 0..63 — one wave
    float invN = 1.0f / (float)n;
    float acc = policy_b[t];
    for (int cc = 0; cc < 32; ++cc) acc += gsum[cc] * invN * policy_W[cc * 64 + t];
    float mx = wmax64(acc);
    float ex = __expf(acc - mx);
    float s = wsum64(ex);
    out[t] = ex / s;
}

extern "C" void kernel_launch(void* const* d_in, const int* in_sizes, int n_in,
                              void* d_out, int out_size, void* d_ws, size_t ws_size,
                              hipStream_t stream) {
    const int* x          = (const int*)d_in[0];
    const int* edge_index = (const int*)d_in[1];
    const int* edge_attr  = (const int*)d_in[2];
    const float* text_emb = (const float*)d_in[3];
    const float* type_emb = (const float*)d_in[4];
    const float* flow_emb = (const float*)d_in[5];
    const float* pos_table= (const float*)d_in[6];
    const float* pos_W    = (const float*)d_in[7];
    const float* pos_b    = (const float*)d_in[8];
    const float* c1_Wl    = (const float*)d_in[9];
    const float* c1_bl    = (const float*)d_in[10];
    const float* c1_Wr    = (const float*)d_in[11];
    const float* c1_br    = (const float*)d_in[12];
    const float* c1_We    = (const float*)d_in[13];
    const float* c1_att   = (const float*)d_in[14];
    const float* c1_bias  = (const float*)d_in[15];
    const float* c2_Wl    = (const float*)d_in[16];
    const float* c2_bl    = (const float*)d_in[17];
    const float* c2_Wr    = (const float*)d_in[18];
    const float* c2_br    = (const float*)d_in[19];
    const float* c2_We    = (const float*)d_in[20];
    const float* c2_att   = (const float*)d_in[21];
    const float* c2_bias  = (const float*)d_in[22];
    const float* policy_W = (const float*)d_in[23];
    const float* policy_b = (const float*)d_in[24];
    float* out = (float*)d_out;

    const int N = in_sizes[0] / 2;   // 50000
    const int E = in_sizes[1] / 2;   // 800000

    // ---- workspace layout ----
    float* fws = (float*)d_ws;
    size_t o = 0;
    float* xl1  = fws + o; o += (size_t)N * 256;
    float* xr1  = fws + o; o += (size_t)N * 256;
    float* h2   = fws + o; o += (size_t)N * 256;
    float* xl2  = fws + o; o += (size_t)N * 32;
    float* xr2  = fws + o; o += (size_t)N * 32;
    float* out2 = fws + o; o += (size_t)N * 32;
    int* iws    = (int*)(fws + o);
    int* cntw   = iws;                // N (histogram, then write-cursor)
    int* rowptr = iws + N;            // N+1
    int* packed = iws + 2 * N + 1;    // E
    int* bsum   = packed + E;         // 64
    int* cnt3   = bsum + 64;          // 4
    size_t tofs = (size_t)(2 * N + 1 + E + 64 + 4);
    tofs = (tofs + 3) & ~(size_t)3;   // 16B alignment for float4 table loads
    float* tabs  = (float*)(iws + tofs);
    float* eaW1   = tabs;             // 3*256
    float* loopW1 = tabs + 768;       // 256
    float* eaW2   = tabs + 1024;      // 3*32
    float* loopW2 = tabs + 1120;      // 32
    float* gsum   = tabs + 1152;      // 32

    // ---- init (ws is poisoned 0xAA every call) ----
    k_zero_all<<<(N + 255) / 256, 256, 0, stream>>>(cntw, N, cnt3, (int*)gsum);

    // ---- constant edge-attr projections ----
    k_flowcnt<<<512, 256, 0, stream>>>(edge_attr, cnt3, E);
    k_prep<<<1, 256, 0, stream>>>(pos_table, pos_W, pos_b, flow_emb, c1_We, c2_We,
                                  cnt3, eaW1, loopW1, eaW2, loopW2, E);

    // ---- CSR build (dst-sorted edge list) ----
    k_hist<<<(E + 255) / 256, 256, 0, stream>>>(edge_index, cntw, E);
    int nb = (N + 1023) / 1024;
    k_scan_block<<<nb, 256, 0, stream>>>(cntw, rowptr, bsum, N);
    k_scan_top<<<1, 64, 0, stream>>>(bsum, rowptr, nb, N);
    k_scan_add<<<(N + 255) / 256, 256, 0, stream>>>(rowptr, bsum, cntw, N);
    k_scatter<<<(E + 255) / 256, 256, 0, stream>>>(edge_index, edge_attr, cntw, packed, E);

    // ---- layer 1 ----
    k_gemm1<<<(N + 15) / 16, 256, 0, stream>>>(x, text_emb, type_emb,
                                               c1_Wl, c1_bl, c1_Wr, c1_br, xl1, xr1, N);
    k_gat256<<<(N + 3) / 4, 256, 0, stream>>>(xl1, xr1, rowptr, packed, eaW1, loopW1,
                                              c1_att, c1_bias, h2, N);

    // ---- layer 2 ----
    k_gemm2<<<(N + 31) / 32, 256, 0, stream>>>(h2, c2_Wl, c2_bl, c2_Wr, c2_br, xl2, xr2, N);
    k_gat32<<<(N + 3) / 4, 256, 0, stream>>>(xl2, xr2, rowptr, packed, eaW2, loopW2,
                                             c2_att, c2_bias, out2, N);

    // ---- readout ----
    k_mean<<<256, 256, 0, stream>>>(out2, gsum, N);
    k_final<<<1, 64, 0, stream>>>(gsum, policy_W, policy_b, out, N);
}